// Round 1
// baseline (142.765 us; speedup 1.0000x reference)
//
#include <hip/hip_runtime.h>

#define B   32
#define C   512
#define HID 32
#define HW  3136        // 56*56
#define HW4 784         // HW/4
#define POS 410         // round(0.8*512); threshold = sorted[POS-1]

// ---------------------------------------------------------------------------
// K1: per-(b,c) channel mean. grid = B*C blocks, 256 threads, float4 loads.
// ---------------------------------------------------------------------------
__global__ __launch_bounds__(256) void mean_kernel(const float* __restrict__ x,
                                                   float* __restrict__ means) {
    const int bc = blockIdx.x;
    const float4* xp = reinterpret_cast<const float4*>(x + (size_t)bc * HW);
    float s = 0.f;
    for (int i = threadIdx.x; i < HW4; i += 256) {
        float4 v = xp[i];
        s += (v.x + v.y) + (v.z + v.w);
    }
    // wave64 butterfly reduce
    #pragma unroll
    for (int off = 32; off > 0; off >>= 1)
        s += __shfl_down(s, off, 64);
    __shared__ float red[4];
    if ((threadIdx.x & 63) == 0) red[threadIdx.x >> 6] = s;
    __syncthreads();
    if (threadIdx.x == 0) {
        float t = (red[0] + red[1]) + (red[2] + red[3]);
        means[bc] = t * (1.0f / HW);
    }
}

// ---------------------------------------------------------------------------
// K2: SE excitation + rank-select threshold + mask. grid = B, block = C.
// ---------------------------------------------------------------------------
__global__ __launch_bounds__(512) void se_kernel(const float* __restrict__ means,
                                                 const float* __restrict__ W1,
                                                 const float* __restrict__ W2,
                                                 float* __restrict__ masks) {
    const int b = blockIdx.x;
    const int t = threadIdx.x;          // 0..511
    __shared__ float m[C];
    __shared__ float y1[HID];
    __shared__ float y2[C];
    __shared__ float thr;

    m[t] = means[b * C + t];
    __syncthreads();

    if (t < HID) {
        const float* w = W1 + t * C;
        float acc = 0.f;
        for (int c = 0; c < C; ++c) acc = fmaf(m[c], w[c], acc);
        y1[t] = fmaxf(acc, 0.f);
    }
    __syncthreads();

    {
        const float* w = W2 + t * HID;
        float acc = 0.f;
        #pragma unroll
        for (int h = 0; h < HID; ++h) acc = fmaf(y1[h], w[h], acc);
        y2[t] = 1.f / (1.f + expf(-acc));
    }
    __syncthreads();

    // rank with index tie-break: exactly one thread has rank == POS-1
    const float v = y2[t];
    int rank = 0;
    for (int j = 0; j < C; ++j) {
        float u = y2[j];                 // broadcast read, no bank conflict
        rank += (u < v || (u == v && j < t)) ? 1 : 0;
    }
    if (rank == POS - 1) thr = v;
    __syncthreads();

    masks[b * C + t] = (v <= thr) ? 1.f : 0.f;
}

// ---------------------------------------------------------------------------
// K3: out = x * mask[bc], float4 grid-stride.
// ---------------------------------------------------------------------------
__global__ __launch_bounds__(256) void scale_kernel(const float* __restrict__ x,
                                                    const float* __restrict__ masks,
                                                    float* __restrict__ out) {
    const float4* xp = reinterpret_cast<const float4*>(x);
    float4* op = reinterpret_cast<float4*>(out);
    const size_t n4 = (size_t)B * C * HW4;          // 12,845,056
    const size_t stride = (size_t)gridDim.x * blockDim.x;
    for (size_t i = (size_t)blockIdx.x * blockDim.x + threadIdx.x; i < n4; i += stride) {
        const int bc = (int)(i / HW4);               // magic-mul, cheap
        const float msk = masks[bc];                 // 64 KB table, L1/L2-hit
        float4 v = xp[i];
        v.x *= msk; v.y *= msk; v.z *= msk; v.w *= msk;
        op[i] = v;
    }
}

extern "C" void kernel_launch(void* const* d_in, const int* in_sizes, int n_in,
                              void* d_out, int out_size, void* d_ws, size_t ws_size,
                              hipStream_t stream) {
    const float* x  = (const float*)d_in[0];
    const float* W1 = (const float*)d_in[1];
    const float* W2 = (const float*)d_in[2];
    float* out = (float*)d_out;

    float* means = (float*)d_ws;                 // B*C floats = 64 KB
    float* masks = means + B * C;                // B*C floats = 64 KB

    mean_kernel<<<B * C, 256, 0, stream>>>(x, means);
    se_kernel<<<B, C, 0, stream>>>(means, W1, W2, masks);

    const int blocks = 2048;                      // grid-stride, ~24 float4/thread
    scale_kernel<<<blocks, 256, 0, stream>>>(x, masks, out);
}

// Round 2
// 109.987 us; speedup vs baseline: 1.2980x; 1.2980x over previous
//
#include <hip/hip_runtime.h>

#define B   32
#define C   512
#define HID 32
#define HW  3136        // 56*56
#define HW4 784         // HW/4
#define POS 410         // round(0.8*512); threshold = sorted[POS-1]

typedef float f32x4 __attribute__((ext_vector_type(4)));

// ---------------------------------------------------------------------------
// K1: per-(b,c) channel mean. One wave per channel, 4 channels per block.
// grid = B*C/4 = 4096 blocks x 256 threads. No LDS, wave-only reduce.
// ---------------------------------------------------------------------------
__global__ __launch_bounds__(256) void mean_kernel(const float* __restrict__ x,
                                                   float* __restrict__ means) {
    const int wave = threadIdx.x >> 6;            // 0..3
    const int lane = threadIdx.x & 63;
    const int bc   = blockIdx.x * 4 + wave;
    const f32x4* xp = reinterpret_cast<const f32x4*>(x + (size_t)bc * HW);
    float s = 0.f;
    for (int i = lane; i < HW4; i += 64) {        // 12-13 float4 per lane
        f32x4 v = xp[i];
        s += (v.x + v.y) + (v.z + v.w);
    }
    #pragma unroll
    for (int off = 32; off > 0; off >>= 1)
        s += __shfl_down(s, off, 64);
    if (lane == 0) means[bc] = s * (1.0f / HW);
}

// ---------------------------------------------------------------------------
// K2: SE excitation + rank-select threshold + mask. grid = B, block = C.
// ---------------------------------------------------------------------------
__global__ __launch_bounds__(512) void se_kernel(const float* __restrict__ means,
                                                 const float* __restrict__ W1,
                                                 const float* __restrict__ W2,
                                                 float* __restrict__ masks) {
    const int b = blockIdx.x;
    const int t = threadIdx.x;          // 0..511
    __shared__ float m[C];
    __shared__ float y1[HID];
    __shared__ float y2[C];
    __shared__ float thr;

    m[t] = means[b * C + t];
    __syncthreads();

    // W1 dot: 16 lanes per hidden unit (h = t>>4, l = t&15), shfl_xor reduce.
    {
        const int h = t >> 4;
        const int l = t & 15;
        const float* w = W1 + h * C;
        float acc = 0.f;
        for (int c = l; c < C; c += 16) acc = fmaf(m[c], w[c], acc);
        #pragma unroll
        for (int off = 8; off > 0; off >>= 1) acc += __shfl_xor(acc, off, 16);
        if (l == 0) y1[h] = fmaxf(acc, 0.f);
    }
    __syncthreads();

    {
        const float* w = W2 + t * HID;
        float acc = 0.f;
        #pragma unroll
        for (int h = 0; h < HID; ++h) acc = fmaf(y1[h], w[h], acc);
        y2[t] = 1.f / (1.f + expf(-acc));
    }
    __syncthreads();

    // rank with index tie-break: exactly one thread has rank == POS-1
    const float v = y2[t];
    int rank = 0;
    for (int j = 0; j < C; ++j) {
        float u = y2[j];                 // broadcast LDS read
        rank += (u < v || (u == v && j < t)) ? 1 : 0;
    }
    if (rank == POS - 1) thr = v;
    __syncthreads();

    masks[b * C + t] = (v <= thr) ? 1.f : 0.f;
}

// ---------------------------------------------------------------------------
// K3: out = x * mask[bc]. One block per channel; mask is wave-uniform.
// mask==0 -> write zeros only (no x read). Non-temporal stores keep x in L3.
// grid = B*C = 16384 blocks x 256 threads.
// ---------------------------------------------------------------------------
__global__ __launch_bounds__(256) void scale_kernel(const float* __restrict__ x,
                                                    const float* __restrict__ masks,
                                                    float* __restrict__ out) {
    const int bc = blockIdx.x;
    const float msk = masks[bc];
    const f32x4* xp = reinterpret_cast<const f32x4*>(x + (size_t)bc * HW);
    f32x4* op = reinterpret_cast<f32x4*>(out + (size_t)bc * HW);
    if (msk != 0.f) {
        for (int i = threadIdx.x; i < HW4; i += 256) {
            f32x4 v = xp[i];
            __builtin_nontemporal_store(v, op + i);
        }
    } else {
        const f32x4 z = {0.f, 0.f, 0.f, 0.f};
        for (int i = threadIdx.x; i < HW4; i += 256) {
            __builtin_nontemporal_store(z, op + i);
        }
    }
}

extern "C" void kernel_launch(void* const* d_in, const int* in_sizes, int n_in,
                              void* d_out, int out_size, void* d_ws, size_t ws_size,
                              hipStream_t stream) {
    const float* x  = (const float*)d_in[0];
    const float* W1 = (const float*)d_in[1];
    const float* W2 = (const float*)d_in[2];
    float* out = (float*)d_out;

    float* means = (float*)d_ws;                 // B*C floats = 64 KB
    float* masks = means + B * C;                // B*C floats = 64 KB

    mean_kernel<<<B * C / 4, 256, 0, stream>>>(x, means);
    se_kernel<<<B, C, 0, stream>>>(means, W1, W2, masks);
    scale_kernel<<<B * C, 256, 0, stream>>>(x, masks, out);
}